// Round 1
// baseline (1849.563 us; speedup 1.0000x reference)
//
#include <hip/hip_runtime.h>
#include <cstdint>

#define U64 unsigned long long

static constexpr int H = 38, W = 50, P = 1900;        // feature map
static constexpr int CIN = 2048, CMID = 256;
static constexpr int NA = 9, NBOX = 17100;            // 1900*9
static constexpr int HP = 40, WP = 52, QP = HP * WP;  // padded positions (2080)
static constexpr int KS = 7, CHUNK = 293;             // split-K over cin
static constexpr int NW = 268;                        // u64 words covering NBOX bits
static constexpr int MSTRIDE = 272;                   // padded mask row stride (u64)
static constexpr float NMS_T = 0.5f;

// ---------------- ws layout (bytes) ----------------
static constexpr size_t SZ_INT  = (size_t)QP * CIN * 4;       // 17,039,360
static constexpr size_t SZ_WT   = (size_t)9 * CIN * CMID * 4; // 18,874,368
static constexpr size_t SZ_PART = (size_t)KS * P * CMID * 4;  // 13,619,200
static constexpr size_t OFF_INT  = 0;
static constexpr size_t OFF_WT   = OFF_INT + SZ_INT;
static constexpr size_t OFF_PART = OFF_WT + SZ_WT;
static constexpr size_t REGA     = OFF_PART + SZ_PART;        // 49,532,928
static constexpr size_t SZ_MASK  = (size_t)NBOX * MSTRIDE * 8;// 37,209,600 (overlays region A)
static constexpr size_t OFF_MASK = 0;
static constexpr size_t OFF_MID  = REGA;                       // [P][CMID] f32
static constexpr size_t OFF_FG   = OFF_MID + 1945600;
static constexpr size_t OFF_BOX  = OFF_FG + 68608;
static constexpr size_t OFF_SBOX = OFF_BOX + 273664;
static constexpr size_t OFF_SAREA= OFF_SBOX + 273664;
static constexpr size_t WS_NEED  = OFF_SAREA + 68608;          // 52,163,072

// ---------------- kernels ----------------

__global__ __launch_bounds__(256) void k_sentinel(float* out, int n) {
    int i = blockIdx.x * 256 + threadIdx.x;
    if (i < n) out[i] = 1.2345678e8f;
}

// feature_map [CIN][H][W] -> in_t [QP][CIN] (padded, zero border; memset first)
__global__ __launch_bounds__(256) void k_in_t(const float* __restrict__ fm, float* __restrict__ in_t) {
    __shared__ float tl[64][53];
    int h = blockIdx.x, cb = blockIdx.y, t = threadIdx.x;
    for (int idx = t; idx < 64 * 50; idx += 256) {
        int ci = idx / 50, w = idx % 50;
        tl[ci][w] = fm[(size_t)(cb * 64 + ci) * (H * W) + h * W + w];
    }
    __syncthreads();
    for (int idx = t; idx < 50 * 64; idx += 256) {
        int w = idx / 64, ci = idx % 64;
        in_t[(size_t)((h + 1) * WP + (w + 1)) * CIN + cb * 64 + ci] = tl[ci][w];
    }
}

// conv_w [CMID][CIN][3][3] -> w_t [9][CIN][CMID]
__global__ __launch_bounds__(256) void k_w_t(const float* __restrict__ cw, float* __restrict__ wt) {
    __shared__ float tl[64][65];
    int x0 = blockIdx.x * 64, c0 = blockIdx.y * 64, t = threadIdx.x;
    for (int rep = 0; rep < 16; ++rep) {
        int lin = rep * 256 + t;
        int row = lin / 64, col = lin % 64; // row: cout offset, col: x offset
        tl[row][col] = cw[(size_t)(c0 + row) * (CIN * 9) + x0 + col];
    }
    __syncthreads();
    for (int rep = 0; rep < 16; ++rep) {
        int lin = rep * 256 + t;
        int xr = lin / 64, cr = lin % 64;
        int x = x0 + xr;
        int k = x % 9, cin = x / 9;
        wt[((size_t)k * CIN + cin) * CMID + c0 + cr] = tl[cr][xr];
    }
}

// 3x3 conv, split-K. grid (9 q-tiles, 4 cout-groups, KS)
__global__ __launch_bounds__(256) void k_conv(const float* __restrict__ in_t,
                                              const float* __restrict__ wt,
                                              float* __restrict__ partial) {
    __shared__ float s_in[4][16][96];   // [x%4][ci][x/4], x in [0,368)
    __shared__ float s_w[16][9][64];    // [ci][k][cout]
    int t = threadIdx.x;
    int tq = t & 63, tc = t >> 6;       // tc == wave id -> s_w reads broadcast
    int q0 = blockIdx.x * 256;
    int cout0 = blockIdx.y * 64;
    int cin0 = blockIdx.z * CHUNK;
    int cin1 = min(CIN, cin0 + CHUNK);
    float acc[4][16];
#pragma unroll
    for (int j = 0; j < 4; ++j)
#pragma unroll
        for (int c = 0; c < 16; ++c) acc[j][c] = 0.f;

    for (int c0 = cin0; c0 < cin1; c0 += 16) {
        // stage input: x covers q0-53 .. q0+314
        for (int idx = t; idx < 16 * 368; idx += 256) {
            int ci = idx & 15, x = idx >> 4;
            int q = q0 - 53 + x;
            float v = 0.f;
            if (c0 + ci < cin1 && q >= 0 && q < QP)
                v = in_t[(size_t)q * CIN + c0 + ci];
            s_in[x & 3][ci][x >> 2] = v;
        }
        // stage weights
        for (int idx = t; idx < 16 * 9 * 64; idx += 256) {
            int c = idx & 63, r = idx >> 6;
            int ci = r / 9, k = r % 9;
            float v = 0.f;
            if (c0 + ci < cin1)
                v = wt[((size_t)k * CIN + (c0 + ci)) * CMID + cout0 + c];
            s_w[ci][k][c] = v;
        }
        __syncthreads();
#pragma unroll 1
        for (int ci = 0; ci < 16; ++ci) {
#pragma unroll
            for (int k = 0; k < 9; ++k) {
                const int dq = (k / 3 - 1) * WP + (k % 3 - 1);
                int xb = tq * 4 + 53 + dq;
                float iv[4];
#pragma unroll
                for (int j = 0; j < 4; ++j) iv[j] = s_in[(xb + j) & 3][ci][(xb + j) >> 2];
                const float4* wp = reinterpret_cast<const float4*>(&s_w[ci][k][tc * 16]);
                float4 w0 = wp[0], w1 = wp[1], w2 = wp[2], w3 = wp[3];
                float wv[16] = {w0.x, w0.y, w0.z, w0.w, w1.x, w1.y, w1.z, w1.w,
                                w2.x, w2.y, w2.z, w2.w, w3.x, w3.y, w3.z, w3.w};
#pragma unroll
                for (int j = 0; j < 4; ++j)
#pragma unroll
                    for (int c = 0; c < 16; ++c) acc[j][c] += iv[j] * wv[c];
            }
        }
        __syncthreads();
    }
    float* part = partial + (size_t)blockIdx.z * P * CMID;
#pragma unroll
    for (int j = 0; j < 4; ++j) {
        int q = q0 + tq * 4 + j;
        if (q < QP) {
            int hp = q / WP, wp_ = q - hp * WP;
            if (hp >= 1 && hp <= H && wp_ >= 1 && wp_ <= W) {
                int p = (hp - 1) * W + (wp_ - 1);
                float4* dst = reinterpret_cast<float4*>(part + (size_t)p * CMID + cout0 + tc * 16);
                dst[0] = make_float4(acc[j][0], acc[j][1], acc[j][2], acc[j][3]);
                dst[1] = make_float4(acc[j][4], acc[j][5], acc[j][6], acc[j][7]);
                dst[2] = make_float4(acc[j][8], acc[j][9], acc[j][10], acc[j][11]);
                dst[3] = make_float4(acc[j][12], acc[j][13], acc[j][14], acc[j][15]);
            }
        }
    }
}

// sum partials + bias + relu -> mid [P][CMID]
__global__ __launch_bounds__(256) void k_reduce(const float* __restrict__ partial,
                                                const float* __restrict__ bias,
                                                float* __restrict__ mid) {
    int p = blockIdx.x, c = threadIdx.x;
    float s = bias[c];
    for (int ks = 0; ks < KS; ++ks) s += partial[(size_t)ks * P * CMID + (size_t)p * CMID + c];
    mid[(size_t)p * CMID + c] = fmaxf(s, 0.f);
}

// 1x1 heads + softmax + anchors + loc2bbox + clip. 4 positions per block.
__global__ __launch_bounds__(256) void k_heads(const float* __restrict__ mid,
                                               const float* __restrict__ score_w,
                                               const float* __restrict__ score_b,
                                               const float* __restrict__ loc_w,
                                               const float* __restrict__ loc_b,
                                               float* __restrict__ score_out,
                                               float* __restrict__ loc_out,
                                               float* __restrict__ anch_out,
                                               float* __restrict__ fg,
                                               float* __restrict__ boxes) {
    __shared__ float wl[256][56];
    __shared__ float bias[56];
    __shared__ float dots[4][64];
    int t = threadIdx.x;
    for (int idx = t; idx < 18 * 256; idx += 256) {
        int c = idx >> 8, i = idx & 255;
        wl[i][c] = score_w[idx];
    }
    for (int idx = t; idx < 36 * 256; idx += 256) {
        int c = idx >> 8, i = idx & 255;
        wl[i][18 + c] = loc_w[idx];
    }
    if (t < 18) bias[t] = score_b[t];
    else if (t < 54) bias[t] = loc_b[t - 18];
    __syncthreads();

    int pl = t >> 6, c = t & 63;
    int p = blockIdx.x * 4 + pl;
    if (c < 54) {
        float d = bias[c];
        const float4* mp = reinterpret_cast<const float4*>(mid + (size_t)p * CMID);
        for (int i4 = 0; i4 < 64; ++i4) {
            float4 m4 = mp[i4];
            int i = i4 * 4;
            d += m4.x * wl[i][c] + m4.y * wl[i + 1][c] + m4.z * wl[i + 2][c] + m4.w * wl[i + 3][c];
        }
        dots[pl][c] = d;
    }
    __syncthreads();

    if (c < NA) {
        int a = c;
        int idx = p * NA + a;
        // softmax pair
        float l0 = dots[pl][2 * a], l1 = dots[pl][2 * a + 1];
        float mx = fmaxf(l0, l1);
        float e0 = expf(l0 - mx), e1 = expf(l1 - mx);
        float den = e0 + e1;
        float s0 = e0 / den, s1 = e1 / den;
        score_out[(size_t)idx * 2 + 0] = s0;
        score_out[(size_t)idx * 2 + 1] = s1;
        fg[idx] = s1;
        // loc
        float dx = dots[pl][18 + 4 * a + 0];
        float dy = dots[pl][18 + 4 * a + 1];
        float dw = dots[pl][18 + 4 * a + 2];
        float dh = dots[pl][18 + 4 * a + 3];
        loc_out[(size_t)idx * 4 + 0] = dx;
        loc_out[(size_t)idx * 4 + 1] = dy;
        loc_out[(size_t)idx * 4 + 2] = dw;
        loc_out[(size_t)idx * 4 + 3] = dh;
        // anchor (f64 base, f32 add -- matches numpy)
        int hh = p / W, ww = p % W;
        const double scales[3] = {8.0, 16.0, 32.0};
        const double ratios[3] = {0.5, 1.0, 2.0};
        double s = scales[a / 3], r = ratios[a % 3];
        double wb = 16.0 * s * sqrt(r);
        double hb = wb / r;
        double xmin = 8.0 - wb / 2.0, ymin = 8.0 - hb / 2.0;
        float b0 = (float)xmin, b1 = (float)ymin;
        float b2 = (float)(xmin + wb), b3 = (float)(ymin + hb);
        float gx = (float)(ww * 16), gy = (float)(hh * 16);
        float a0 = gx + b0, a1 = gy + b1, a2 = gx + b2, a3 = gy + b3;
        anch_out[(size_t)idx * 4 + 0] = a0;
        anch_out[(size_t)idx * 4 + 1] = a1;
        anch_out[(size_t)idx * 4 + 2] = a2;
        anch_out[(size_t)idx * 4 + 3] = a3;
        // loc2bbox + clip
        float aw = a2 - a0, ah = a3 - a1;
        float cx = a0 + 0.5f * aw, cy = a1 + 0.5f * ah;
        float ncx = dx * aw + cx, ncy = dy * ah + cy;
        float nw = expf(dw) * aw, nh = expf(dh) * ah;
        float x1 = ncx - 0.5f * nw, y1 = ncy - 0.5f * nh;
        float x2 = ncx + 0.5f * nw, y2 = ncy + 0.5f * nh;
        x1 = fminf(fmaxf(x1, 0.f), (float)(W * 16));
        x2 = fminf(fmaxf(x2, 0.f), (float)(W * 16));
        y1 = fminf(fmaxf(y1, 0.f), (float)(H * 16));
        y2 = fminf(fmaxf(y2, 0.f), (float)(H * 16));
        float4* bp = reinterpret_cast<float4*>(boxes);
        bp[idx] = make_float4(x1, y1, x2, y2);
    }
}

// stable descending rank; scatter boxes to sorted order
__global__ __launch_bounds__(256) void k_rank(const float* __restrict__ fg,
                                              const float* __restrict__ boxes,
                                              float* __restrict__ sboxes,
                                              float* __restrict__ sarea) {
    __shared__ float tile[1024];
    int t = threadIdx.x;
    int i = blockIdx.x * 256 + t;
    float my = (i < NBOX) ? fg[i] : 0.f;
    int cnt = 0;
    for (int jt = 0; jt < 17; ++jt) {
        for (int u = t; u < 1024; u += 256) {
            int j = jt * 1024 + u;
            tile[u] = (j < NBOX) ? fg[j] : -3.4e38f;
        }
        __syncthreads();
        if (i < NBOX) {
            int jb = jt * 1024;
            for (int u = 0; u < 1024; ++u) {
                float sj = tile[u];
                cnt += (sj > my) || (sj == my && (jb + u) < i);
            }
        }
        __syncthreads();
    }
    if (i < NBOX) {
        float4 b = reinterpret_cast<const float4*>(boxes)[i];
        reinterpret_cast<float4*>(sboxes)[cnt] = b;
        sarea[cnt] = (b.z - b.x) * (b.w - b.y);
    }
}

// NMS pair bitmask: mask[i][w] bit jb = (IoU(i, w*64+jb) > T && j > i)
__global__ __launch_bounds__(256) void k_maskfill(const float* __restrict__ sboxes,
                                                  const float* __restrict__ sarea,
                                                  U64* __restrict__ mask) {
    int w = blockIdx.y;
    int i0 = blockIdx.x * 256;
    if (w < (i0 >> 6)) return;
    __shared__ float4 sb[64];
    __shared__ float sa[64];
    int t = threadIdx.x;
    if (t < 64) {
        int j = w * 64 + t;
        if (j < NBOX) {
            sb[t] = reinterpret_cast<const float4*>(sboxes)[j];
            sa[t] = sarea[j];
        } else {
            sb[t] = make_float4(0.f, 0.f, 0.f, 0.f);
            sa[t] = 0.f;
        }
    }
    __syncthreads();
    int i = i0 + t;
    if (i >= NBOX || w < (i >> 6)) return;
    float4 bi = reinterpret_cast<const float4*>(sboxes)[i];
    float ai = sarea[i];
    U64 word = 0;
#pragma unroll 4
    for (int jb = 0; jb < 64; ++jb) {
        int j = w * 64 + jb;
        float4 bj = sb[jb];
        float xx1 = fmaxf(bi.x, bj.x), yy1 = fmaxf(bi.y, bj.y);
        float xx2 = fminf(bi.z, bj.z), yy2 = fminf(bi.w, bj.w);
        float inter = fmaxf(xx2 - xx1, 0.f) * fmaxf(yy2 - yy1, 0.f);
        float iou = inter / (ai + sa[jb] - inter);
        word |= ((U64)((iou > NMS_T) && (j > i))) << jb;
    }
    mask[(size_t)i * MSTRIDE + w] = word;
}

// exact greedy sweep, 64-box groups, single block
__global__ __launch_bounds__(256) void k_sweep(const U64* __restrict__ mask,
                                               const float* __restrict__ sboxes,
                                               float* __restrict__ rois_out,
                                               float* __restrict__ keep_out) {
    __shared__ U64 rem[NW];
    __shared__ U64 iw[64];
    __shared__ unsigned base_s;
    int t = threadIdx.x;
    for (int u = t; u < NW; u += 256) rem[u] = 0;
    if (t == 0) base_s = 0;
    __syncthreads();
    for (int g = 0; g < NW; ++g) {
        int nv = min(64, NBOX - g * 64);
        if (t < 64) {
            U64 intra = 0;
            if (t < nv) intra = mask[(size_t)(g * 64 + t) * MSTRIDE + g];
            iw[t] = intra;
        }
        __syncthreads();
        U64 vmask = (nv == 64) ? ~0ull : ((1ull << nv) - 1);
        U64 m = rem[g];
        for (int ii = 0; ii < 64; ++ii) {
            if (!((m >> ii) & 1ull)) m |= iw[ii];
        }
        U64 kept = ~m & vmask;
        unsigned base = base_s;
        if (t < 64) {
            bool mk = (t < nv) && ((kept >> t) & 1ull);
            if (mk) {
                unsigned pre = (t == 0) ? 0u : (unsigned)__popcll(kept & ((1ull << t) - 1));
                unsigned dst = base + pre;
                float4 bb = reinterpret_cast<const float4*>(sboxes)[g * 64 + t];
                reinterpret_cast<float4*>(rois_out)[dst] = bb;
                keep_out[dst] = 1.0f;
            }
        }
        __syncthreads();
        if (t == 0) {
            rem[g] = m;
            base_s = base + (unsigned)__popcll(kept);
        }
        // cross-group suppression: OR kept rows into rem[w>g]
        U64 kw = kept;
        for (int w = g + 1 + t; w < NW; w += 256) {
            U64 acc = rem[w];
            U64 tmp = kw;
            while (tmp) {
                int b0 = __builtin_ctzll(tmp); tmp &= tmp - 1;
                int b1 = -1, b2 = -1, b3 = -1;
                if (tmp) { b1 = __builtin_ctzll(tmp); tmp &= tmp - 1; }
                if (tmp) { b2 = __builtin_ctzll(tmp); tmp &= tmp - 1; }
                if (tmp) { b3 = __builtin_ctzll(tmp); tmp &= tmp - 1; }
                U64 v0 = mask[(size_t)(g * 64 + b0) * MSTRIDE + w];
                U64 v1 = (b1 >= 0) ? mask[(size_t)(g * 64 + b1) * MSTRIDE + w] : 0;
                U64 v2 = (b2 >= 0) ? mask[(size_t)(g * 64 + b2) * MSTRIDE + w] : 0;
                U64 v3 = (b3 >= 0) ? mask[(size_t)(g * 64 + b3) * MSTRIDE + w] : 0;
                acc |= v0 | v1 | v2 | v3;
            }
            rem[w] = acc;
        }
        __syncthreads();
    }
}

// ---------------- launch ----------------
extern "C" void kernel_launch(void* const* d_in, const int* in_sizes, int n_in,
                              void* d_out, int out_size, void* d_ws, size_t ws_size,
                              hipStream_t stream) {
    const float* fm      = (const float*)d_in[0];
    const float* conv_w  = (const float*)d_in[2];
    const float* conv_b  = (const float*)d_in[3];
    const float* score_w = (const float*)d_in[4];
    const float* score_b = (const float*)d_in[5];
    const float* loc_w   = (const float*)d_in[6];
    const float* loc_b   = (const float*)d_in[7];

    float* out = (float*)d_out;
    float* rois_out  = out;
    float* keep_out  = out + NBOX * 4;
    float* anch_out  = out + NBOX * 5;
    float* loc_out   = out + NBOX * 9;
    float* score_out = out + NBOX * 13;

    if (ws_size < WS_NEED) {
        k_sentinel<<<(out_size + 255) / 256, 256, 0, stream>>>(out, out_size);
        return;
    }

    char* ws = (char*)d_ws;
    float* in_t    = (float*)(ws + OFF_INT);
    float* wt      = (float*)(ws + OFF_WT);
    float* partial = (float*)(ws + OFF_PART);
    U64*   mask    = (U64*)(ws + OFF_MASK);
    float* mid     = (float*)(ws + OFF_MID);
    float* fg      = (float*)(ws + OFF_FG);
    float* boxes   = (float*)(ws + OFF_BOX);
    float* sboxes  = (float*)(ws + OFF_SBOX);
    float* sarea   = (float*)(ws + OFF_SAREA);

    hipMemsetAsync(in_t, 0, SZ_INT, stream);
    k_in_t<<<dim3(H, CIN / 64), 256, 0, stream>>>(fm, in_t);
    k_w_t<<<dim3(CIN * 9 / 64, CMID / 64), 256, 0, stream>>>(conv_w, wt);
    k_conv<<<dim3(9, 4, KS), 256, 0, stream>>>(in_t, wt, partial);
    k_reduce<<<P, 256, 0, stream>>>(partial, conv_b, mid);
    k_heads<<<P / 4, 256, 0, stream>>>(mid, score_w, score_b, loc_w, loc_b,
                                       score_out, loc_out, anch_out, fg, boxes);
    k_rank<<<(NBOX + 255) / 256, 256, 0, stream>>>(fg, boxes, sboxes, sarea);
    hipMemsetAsync(rois_out, 0, (size_t)NBOX * 5 * 4, stream);  // rois_out + keep
    k_maskfill<<<dim3((NBOX + 255) / 256, NW), 256, 0, stream>>>(sboxes, sarea, mask);
    k_sweep<<<1, 256, 0, stream>>>(mask, sboxes, rois_out, keep_out);
}